// Round 8
// baseline (289.911 us; speedup 1.0000x reference)
//
#include <hip/hip_runtime.h>

#define D_FEAT 256
#define UNITS  128

#define NBITS  7            // coarse bin = 128 dst
#define BINSZ  128
#define BINCAP 2432         // Poisson(2048) + 8.5 sigma — cannot overflow for random dst
#define MAXNB  800          // >= ceil(100000/128) = 782

typedef __attribute__((ext_vector_type(8))) short short8;   // 8 bf16 (4 VGPRs)
typedef __attribute__((ext_vector_type(4))) float floatx4;

__device__ inline ushort f2bf(float f) {          // fp32 -> bf16, round-nearest-even
    uint u = __float_as_uint(f);
    uint r = u + 0x7FFF + ((u >> 16) & 1);
    return (ushort)(r >> 16);
}

// ---------------------------------------------------------------------------
// One-time prep: wT_bf16[n][k] = bf16(w[k][n]); 128 x 256, 64 KB, L2-resident.
// Also zeroes the scatter cursor (folds away the hipMemsetAsync dispatch).
// ---------------------------------------------------------------------------
__global__ __launch_bounds__(256) void wt_prep_kernel(const float* __restrict__ w,
                                                      ushort* __restrict__ wT,
                                                      int* __restrict__ cursor, int ncur) {
    int idx = blockIdx.x * 256 + threadIdx.x;     // 32768 threads
    int n = idx >> 8;
    int k = idx & 255;
    wT[n * 256 + k] = f2bf(w[(size_t)k * UNITS + n]);
    if (idx < ncur) cursor[idx] = 0;
}

// ---------------------------------------------------------------------------
// FUSED gemm ∪ scatter, v2 (round 8). Round-6's fusion failed for two now-
// fixed reasons: scatter blocks at 256t had only 8 waves/CU under the 64 KB
// LDS cap, and scatter-first ordering. This version:
//   * 512-thread uniform blocks: 2 blocks/CU x 8 waves = 16 waves/CU for
//     BOTH personalities (gemm body = round-7's verified v4, verbatim).
//   * interleaved routing: odd bid < 512 -> scatter chunk (256 chunks of
//     6250 edges, same staged-run length as standalone), so each CU co-hosts
//     one gemm + one scatter block from t=0 (MFMA pipe + memory path
//     time-share instead of stream-serializing ~70 us of independent work).
//   * LDS aliased: gemm uses 64 KB for wT; scatter uses 6.4 KB for hist/base.
// ---------------------------------------------------------------------------
__global__ __launch_bounds__(512, 4) void gemm_scatter2_kernel(
        const float* __restrict__ x, const ushort* __restrict__ wT,
        ushort* __restrict__ hb, int M,
        const int* __restrict__ src, const int* __restrict__ dst,
        const float* __restrict__ vals,
        int* __restrict__ cursor, int2* __restrict__ staged,
        int E, int NB, int chunk) {
    __shared__ __align__(16) char smem[65536];
    const int tid = threadIdx.x;
    const int bid = blockIdx.x;

    const bool is_scatter = (bid < 512) && (bid & 1);

    if (is_scatter) {
        // ---------------- scatter body (512 threads, chunk 6250) ----------
        int* s_hist = (int*)smem;
        int* s_base = s_hist + MAXNB;
        const int T  = 512;
        const int sb = bid >> 1;              // 0..255
        const int e0 = sb * chunk;
        const int e1 = min(E, e0 + chunk);

        for (int i = tid; i < NB; i += T) s_hist[i] = 0;
        __syncthreads();

        for (int e = e0 + tid; e < e1; e += T)
            atomicAdd(&s_hist[dst[e] >> NBITS], 1);
        __syncthreads();

        for (int b = tid; b < NB; b += T) {
            int c = s_hist[b];
            s_base[b] = (c > 0) ? atomicAdd(&cursor[b * 4], c) : 0;
        }
        __syncthreads();
        for (int i = tid; i < NB; i += T) s_hist[i] = 0;   // reuse as rank counter
        __syncthreads();

        for (int e = e0 + tid; e < e1; e += T) {
            int d = dst[e];
            int b = d >> NBITS;
            int r = s_base[b] + atomicAdd(&s_hist[b], 1);
            if (r < BINCAP) {
                int meta = src[e] | ((d & (BINSZ - 1)) << 20);
                staged[(size_t)b * BINCAP + r] = make_int2(meta, __float_as_int(vals[e]));
            }
        }
        return;
    }

    // ---------------- gemm body (round-7 v4, gb-routed) ----------------
    // gb: even bids in [0,512) -> 0..255; bids [512,1038) -> 256..781.
    ushort* lds_w = (ushort*)smem;    // 64 KB: row n = out-col, 32 x 16B slots, slot^=(n&7)

    const int gb   = (bid < 512) ? (bid >> 1) : (bid - 256);
    const int wave = tid >> 6;            // 0..7
    const int lane = tid & 63;
    const int quad = lane >> 4;
    const int m16  = lane & 15;

    const int row  = gb * 128 + wave * 16 + m16;
    const int rowc = row < M ? row : M - 1;
    const float* xr = x + (size_t)rowc * D_FEAT;

    // ---- phase 0: issue the 8 wT 16B-chunk loads (L2-hot) ----
    short8 wv[8];
    #pragma unroll
    for (int r = 0; r < 8; ++r)
        wv[r] = *(const short8*)(wT + (size_t)(r * 512 + tid) * 8);
    __builtin_amdgcn_sched_barrier(0);

    // ---- phase 1: issue ALL 16 x loads (256 B/lane in flight, HBM) ----
    float4 xv[16];
    #pragma unroll
    for (int s = 0; s < 8; ++s) {
        const float4* p = (const float4*)(xr + s * 32 + quad * 8);
        xv[2 * s]     = p[0];
        xv[2 * s + 1] = p[1];
    }
    __builtin_amdgcn_sched_barrier(0);

    // ---- phase 2: LDS-write wT, XOR-swizzled (waits only the wv loads) ----
    #pragma unroll
    for (int r = 0; r < 8; ++r) {
        int ci = r * 512 + tid;          // 16B chunk index: row = ci>>5, slot = ci&31
        int n  = ci >> 5;
        int ts = (ci & 31) ^ (n & 7);    // swizzled slot
        *(short8*)(lds_w + n * 256 + ts * 8) = wv[r];
    }
    __builtin_amdgcn_sched_barrier(0);

    // ---- phase 3: convert x to bf16 A-fragments (waits the x loads) ----
    short8 afrag[8];
    #pragma unroll
    for (int s = 0; s < 8; ++s) {
        float4 lo = xv[2 * s];
        float4 hi = xv[2 * s + 1];
        union { short8 v; ushort u[8]; } af;
        af.u[0] = f2bf(lo.x); af.u[1] = f2bf(lo.y);
        af.u[2] = f2bf(lo.z); af.u[3] = f2bf(lo.w);
        af.u[4] = f2bf(hi.x); af.u[5] = f2bf(hi.y);
        af.u[6] = f2bf(hi.z); af.u[7] = f2bf(hi.w);
        afrag[s] = af.v;
    }

    __syncthreads();

    // ---- phase 4: MFMA main loop; B-frags via swizzled ds_read_b128 ----
    floatx4 acc[8] = {};
    #pragma unroll
    for (int s = 0; s < 8; ++s) {
        #pragma unroll
        for (int c = 0; c < 8; ++c) {
            int rowb = c * 16 + m16;
            int ts   = (s * 4 + quad) ^ (m16 & 7);
            short8 bfrag = *(const short8*)(lds_w + rowb * 256 + ts * 8);
            acc[c] = __builtin_amdgcn_mfma_f32_16x16x32_bf16(afrag[s], bfrag, acc[c], 0, 0, 0);
        }
    }

    // ---- epilogue: D[row=quad*4+i][col=c*16+m16] -> bf16 ----
    #pragma unroll
    for (int c = 0; c < 8; ++c) {
        #pragma unroll
        for (int i = 0; i < 4; ++i) {
            int r = gb * 128 + wave * 16 + quad * 4 + i;
            if (r < M) hb[(size_t)r * UNITS + c * 16 + m16] = f2bf(acc[c][i]);
        }
    }
}

// ---------------------------------------------------------------------------
// Gather (round-7 form, unchanged — seventh consecutive ~63-66 us across
// occupancy 27-61% and five pipeline structures: saturated L2-miss path,
// ~179 MB L2-fill per dispatch at ~2.7 TB/s).
// ---------------------------------------------------------------------------
#define ACC8(h, v)                                  \
    a0 += (v) * __uint_as_float((h).x << 16);       \
    a1 += (v) * __uint_as_float((h).x & 0xFFFF0000u); \
    a2 += (v) * __uint_as_float((h).y << 16);       \
    a3 += (v) * __uint_as_float((h).y & 0xFFFF0000u); \
    a4 += (v) * __uint_as_float((h).z << 16);       \
    a5 += (v) * __uint_as_float((h).z & 0xFFFF0000u); \
    a6 += (v) * __uint_as_float((h).w << 16);       \
    a7 += (v) * __uint_as_float((h).w & 0xFFFF0000u);

__global__ __launch_bounds__(512) void gather_sort_kernel(const int* __restrict__ cursor,
                                                          const int2* __restrict__ staged,
                                                          const ushort* __restrict__ hb,
                                                          float* __restrict__ out, int N) {
    __shared__ int2 sraw[BINCAP];
    __shared__ int2 sbuf[BINCAP];
    __shared__ int cnt[BINSZ], ofs[BINSZ], cur[BINSZ];
    __shared__ int gofs[16];

    const int b   = blockIdx.x;
    const int tid = threadIdx.x;

    int n = cursor[b * 4];
    if (n > BINCAP) n = BINCAP;

    for (int i = tid; i < BINSZ; i += 512) cnt[i] = 0;
    __syncthreads();

    const int2* sg = staged + (size_t)b * BINCAP;

    // pass 1: histogram + park raw entries in LDS
    for (int i = tid; i < n; i += 512) {
        int2 e = sg[i];
        sraw[i] = e;
        atomicAdd(&cnt[(e.x >> 20) & (BINSZ - 1)], 1);
    }
    __syncthreads();

    // two-level exclusive prefix scan over cnt[128]
    if (tid < 16) {
        int s = 0;
        #pragma unroll
        for (int j = 0; j < 8; ++j) s += cnt[tid * 8 + j];
        gofs[tid] = s;
    }
    __syncthreads();
    if (tid == 0) {
        int run = 0;
        #pragma unroll
        for (int g = 0; g < 16; ++g) { int c = gofs[g]; gofs[g] = run; run += c; }
    }
    __syncthreads();
    if (tid < 16) {
        int run = gofs[tid];
        #pragma unroll
        for (int j = 0; j < 8; ++j) {
            int d = tid * 8 + j;
            int c = cnt[d];
            ofs[d] = run; cur[d] = run; run += c;
        }
    }
    __syncthreads();

    // pass 2: place sorted (LDS -> LDS)
    for (int i = tid; i < n; i += 512) {
        int2 e = sraw[i];
        int pos = atomicAdd(&cur[(e.x >> 20) & (BINSZ - 1)], 1);
        sbuf[pos] = e;
    }
    __syncthreads();

    // quarter-wave accumulate: executor = wave*4 + quarter (32 per block)
    const int ex = (tid >> 6) * 4 + ((tid & 63) >> 4);
    const int m  = tid & 15;

    #pragma unroll
    for (int r = 0; r < 4; ++r) {
        int d  = r * 32 + ex;
        int dg = b * BINSZ + d;
        if (dg >= N) continue;
        int start = ofs[d];
        int c     = cnt[d];

        float a0 = 0.f, a1 = 0.f, a2 = 0.f, a3 = 0.f;
        float a4 = 0.f, a5 = 0.f, a6 = 0.f, a7 = 0.f;
        int j = 0;
        for (; j + 8 <= c; j += 8) {
            int2 e0 = sbuf[start + j];
            int2 e1 = sbuf[start + j + 1];
            int2 e2 = sbuf[start + j + 2];
            int2 e3 = sbuf[start + j + 3];
            int2 e4 = sbuf[start + j + 4];
            int2 e5 = sbuf[start + j + 5];
            int2 e6 = sbuf[start + j + 6];
            int2 e7 = sbuf[start + j + 7];
            __builtin_amdgcn_sched_barrier(0);     // NOTHING crosses
            uint4 h0 = *(const uint4*)(hb + (size_t)(e0.x & 0xFFFFF) * UNITS + m * 8);
            uint4 h1 = *(const uint4*)(hb + (size_t)(e1.x & 0xFFFFF) * UNITS + m * 8);
            uint4 h2 = *(const uint4*)(hb + (size_t)(e2.x & 0xFFFFF) * UNITS + m * 8);
            uint4 h3 = *(const uint4*)(hb + (size_t)(e3.x & 0xFFFFF) * UNITS + m * 8);
            uint4 h4 = *(const uint4*)(hb + (size_t)(e4.x & 0xFFFFF) * UNITS + m * 8);
            uint4 h5 = *(const uint4*)(hb + (size_t)(e5.x & 0xFFFFF) * UNITS + m * 8);
            uint4 h6 = *(const uint4*)(hb + (size_t)(e6.x & 0xFFFFF) * UNITS + m * 8);
            uint4 h7 = *(const uint4*)(hb + (size_t)(e7.x & 0xFFFFF) * UNITS + m * 8);
            __builtin_amdgcn_sched_barrier(0);     // all 8 loads issued before any ACC
            float v0 = __int_as_float(e0.y);
            float v1 = __int_as_float(e1.y);
            float v2 = __int_as_float(e2.y);
            float v3 = __int_as_float(e3.y);
            float v4 = __int_as_float(e4.y);
            float v5 = __int_as_float(e5.y);
            float v6 = __int_as_float(e6.y);
            float v7 = __int_as_float(e7.y);
            ACC8(h0, v0)
            ACC8(h1, v1)
            ACC8(h2, v2)
            ACC8(h3, v3)
            ACC8(h4, v4)
            ACC8(h5, v5)
            ACC8(h6, v6)
            ACC8(h7, v7)
        }
        if (j + 4 <= c) {
            int2 e0 = sbuf[start + j];
            int2 e1 = sbuf[start + j + 1];
            int2 e2 = sbuf[start + j + 2];
            int2 e3 = sbuf[start + j + 3];
            __builtin_amdgcn_sched_barrier(0);
            uint4 h0 = *(const uint4*)(hb + (size_t)(e0.x & 0xFFFFF) * UNITS + m * 8);
            uint4 h1 = *(const uint4*)(hb + (size_t)(e1.x & 0xFFFFF) * UNITS + m * 8);
            uint4 h2 = *(const uint4*)(hb + (size_t)(e2.x & 0xFFFFF) * UNITS + m * 8);
            uint4 h3 = *(const uint4*)(hb + (size_t)(e3.x & 0xFFFFF) * UNITS + m * 8);
            __builtin_amdgcn_sched_barrier(0);
            float v0 = __int_as_float(e0.y);
            float v1 = __int_as_float(e1.y);
            float v2 = __int_as_float(e2.y);
            float v3 = __int_as_float(e3.y);
            ACC8(h0, v0)
            ACC8(h1, v1)
            ACC8(h2, v2)
            ACC8(h3, v3)
            j += 4;
        }
        for (; j < c; ++j) {
            int2 e0 = sbuf[start + j];
            uint4 h0 = *(const uint4*)(hb + (size_t)(e0.x & 0xFFFFF) * UNITS + m * 8);
            float v0 = __int_as_float(e0.y);
            ACC8(h0, v0)
        }

        float* op = out + (size_t)dg * UNITS + m * 8;
        *(floatx4*)op       = (floatx4){a0, a1, a2, a3};
        *(floatx4*)(op + 4) = (floatx4){a4, a5, a6, a7};
    }
}

extern "C" void kernel_launch(void* const* d_in, const int* in_sizes, int n_in,
                              void* d_out, int out_size, void* d_ws, size_t ws_size,
                              hipStream_t stream) {
    const float* x        = (const float*)d_in[0];
    const float* w        = (const float*)d_in[1];
    const int*   adj_src  = (const int*)d_in[2];
    const int*   adj_dst  = (const int*)d_in[3];
    const float* adj_vals = (const float*)d_in[4];
    float*       out      = (float*)d_out;

    const int M = in_sizes[0] / D_FEAT;   // 100000 nodes
    const int E = in_sizes[2];            // 1600000 edges
    const int NB = (M + BINSZ - 1) >> NBITS;   // 782 coarse bins

    // Workspace:
    //   hb:     M*128*2           = 25.6 MB
    //   wT:     128*256*2         = 64 KB
    //   cursor: NB*4 ints         = 12.5 KB
    //   staged: NB*BINCAP*8       = 15.2 MB
    char*   ws  = (char*)d_ws;
    ushort* hb  = (ushort*)ws;
    size_t  off = (size_t)M * UNITS * sizeof(ushort);
    off = (off + 255) & ~(size_t)255;
    ushort* wT  = (ushort*)(ws + off);
    off += (size_t)128 * 256 * sizeof(ushort);
    int*    cursor = (int*)(ws + off);
    off += (size_t)NB * 4 * sizeof(int);
    off = (off + 15) & ~(size_t)15;
    int2*   staged = (int2*)(ws + off);

    wt_prep_kernel<<<128, 256, 0, stream>>>(w, wT, cursor, NB * 4);

    // 256 scatter chunks (6250 edges each) interleaved with 782 gemm tiles:
    // odd bid < 512 -> scatter; else gemm. Total 1038 blocks of 512 threads.
    const int NSCAT = 256;
    const int chunk = (E + NSCAT - 1) / NSCAT;
    const int NGEMM = (M + 127) / 128;          // 782
    gemm_scatter2_kernel<<<NSCAT + NGEMM, 512, 0, stream>>>(
        x, wT, hb, M, adj_src, adj_dst, adj_vals, cursor, staged, E, NB, chunk);

    gather_sort_kernel<<<NB, 512, 0, stream>>>(cursor, staged, hb, out, M);
}

// Round 9
// 285.279 us; speedup vs baseline: 1.0162x; 1.0162x over previous
//
#include <hip/hip_runtime.h>

#define D_FEAT 256
#define UNITS  128

#define NBITS  7            // coarse bin = 128 dst
#define BINSZ  128
#define BINCAP 2432         // Poisson(2048) + 8.5 sigma — cannot overflow for random dst
#define MAXNB  800          // >= ceil(100000/128) = 782

typedef __attribute__((ext_vector_type(8))) short short8;   // 8 bf16 (4 VGPRs)
typedef __attribute__((ext_vector_type(4))) float floatx4;

__device__ inline ushort f2bf(float f) {          // fp32 -> bf16, round-nearest-even
    uint u = __float_as_uint(f);
    uint r = u + 0x7FFF + ((u >> 16) & 1);
    return (ushort)(r >> 16);
}

// ---------------------------------------------------------------------------
// One-time prep: wT_bf16[n][k] = bf16(w[k][n]); 128 x 256, 64 KB, L2-resident.
// Also zeroes the scatter cursor (folds away the hipMemsetAsync dispatch).
// ---------------------------------------------------------------------------
__global__ __launch_bounds__(256) void wt_prep_kernel(const float* __restrict__ w,
                                                      ushort* __restrict__ wT,
                                                      int* __restrict__ cursor, int ncur) {
    int idx = blockIdx.x * 256 + threadIdx.x;     // 32768 threads
    int n = idx >> 8;
    int k = idx & 255;
    wT[n * 256 + k] = f2bf(w[(size_t)k * UNITS + n]);
    if (idx < ncur) cursor[idx] = 0;
}

// ---------------------------------------------------------------------------
// GEMM v4 (round-7 verified best): v3's per-wave body (sched_barrier(0)-
// pinned 16-deep x-load phase, XOR-swizzled wT in LDS) at 512 threads /
// 128 rows per block -> 16 waves/CU. Round-8 lesson: do NOT co-compile a
// scatter branch into this kernel — the fused variant dropped VGPR 88->56
// (allocator un-pinned the load phase) and ran 97 us.
// ---------------------------------------------------------------------------
__global__ __launch_bounds__(512, 4) void gemm_mfma4_kernel(const float* __restrict__ x,
                                                            const ushort* __restrict__ wT,
                                                            ushort* __restrict__ hb, int M) {
    __shared__ ushort lds_w[128 * 256];   // 64 KB: row n = out-col, 32 x 16B slots, slot^=(n&7)

    const int tid  = threadIdx.x;
    const int wave = tid >> 6;            // 0..7
    const int lane = tid & 63;
    const int quad = lane >> 4;
    const int m16  = lane & 15;

    const int row  = blockIdx.x * 128 + wave * 16 + m16;
    const int rowc = row < M ? row : M - 1;
    const float* xr = x + (size_t)rowc * D_FEAT;

    // ---- phase 0: issue the 8 wT 16B-chunk loads (L2-hot) ----
    short8 wv[8];
    #pragma unroll
    for (int r = 0; r < 8; ++r)
        wv[r] = *(const short8*)(wT + (size_t)(r * 512 + tid) * 8);
    __builtin_amdgcn_sched_barrier(0);

    // ---- phase 1: issue ALL 16 x loads (256 B/lane in flight, HBM) ----
    float4 xv[16];
    #pragma unroll
    for (int s = 0; s < 8; ++s) {
        const float4* p = (const float4*)(xr + s * 32 + quad * 8);
        xv[2 * s]     = p[0];
        xv[2 * s + 1] = p[1];
    }
    __builtin_amdgcn_sched_barrier(0);

    // ---- phase 2: LDS-write wT, XOR-swizzled (waits only the wv loads) ----
    #pragma unroll
    for (int r = 0; r < 8; ++r) {
        int ci = r * 512 + tid;          // 16B chunk index: row = ci>>5, slot = ci&31
        int n  = ci >> 5;
        int ts = (ci & 31) ^ (n & 7);    // swizzled slot
        *(short8*)(lds_w + n * 256 + ts * 8) = wv[r];
    }
    __builtin_amdgcn_sched_barrier(0);

    // ---- phase 3: convert x to bf16 A-fragments (waits the x loads) ----
    short8 afrag[8];
    #pragma unroll
    for (int s = 0; s < 8; ++s) {
        float4 lo = xv[2 * s];
        float4 hi = xv[2 * s + 1];
        union { short8 v; ushort u[8]; } af;
        af.u[0] = f2bf(lo.x); af.u[1] = f2bf(lo.y);
        af.u[2] = f2bf(lo.z); af.u[3] = f2bf(lo.w);
        af.u[4] = f2bf(hi.x); af.u[5] = f2bf(hi.y);
        af.u[6] = f2bf(hi.z); af.u[7] = f2bf(hi.w);
        afrag[s] = af.v;
    }

    __syncthreads();

    // ---- phase 4: MFMA main loop; B-frags via swizzled ds_read_b128 ----
    floatx4 acc[8] = {};
    #pragma unroll
    for (int s = 0; s < 8; ++s) {
        #pragma unroll
        for (int c = 0; c < 8; ++c) {
            int rowb = c * 16 + m16;
            int ts   = (s * 4 + quad) ^ (m16 & 7);
            short8 bfrag = *(const short8*)(lds_w + rowb * 256 + ts * 8);
            acc[c] = __builtin_amdgcn_mfma_f32_16x16x32_bf16(afrag[s], bfrag, acc[c], 0, 0, 0);
        }
    }

    // ---- epilogue: D[row=quad*4+i][col=c*16+m16] -> bf16 ----
    #pragma unroll
    for (int c = 0; c < 8; ++c) {
        #pragma unroll
        for (int i = 0; i < 4; ++i) {
            int r = blockIdx.x * 128 + wave * 16 + quad * 4 + i;
            if (r < M) hb[(size_t)r * UNITS + c * 16 + m16] = f2bf(acc[c][i]);
        }
    }
}

// ---------------------------------------------------------------------------
// Coarse scatter (round-1 direct form, NBITS 7): 256 chunks x 1024 threads,
// per-chunk LDS histogram, one cursor reservation per (block,bin), direct
// staged writes. 128-dst bins -> ~8-entry (64 B) runs per (block,bin).
// staged entry: {meta = src | (dst&127)<<20, bits(val)}
// ---------------------------------------------------------------------------
__global__ __launch_bounds__(1024) void coarse_scatter_kernel(const int* __restrict__ src,
                                                              const int* __restrict__ dst,
                                                              const float* __restrict__ vals,
                                                              int* __restrict__ cursor,   // stride 4 ints/bin
                                                              int2* __restrict__ staged,
                                                              int E, int NB, int chunk) {
    __shared__ int s_hist[MAXNB];
    __shared__ int s_base[MAXNB];

    const int tid = threadIdx.x;
    const int T   = 1024;
    const int e0 = blockIdx.x * chunk;
    const int e1 = min(E, e0 + chunk);

    for (int i = tid; i < NB; i += T) s_hist[i] = 0;
    __syncthreads();

    for (int e = e0 + tid; e < e1; e += T)
        atomicAdd(&s_hist[dst[e] >> NBITS], 1);
    __syncthreads();

    for (int b = tid; b < NB; b += T) {
        int c = s_hist[b];
        s_base[b] = (c > 0) ? atomicAdd(&cursor[b * 4], c) : 0;
    }
    __syncthreads();
    for (int i = tid; i < NB; i += T) s_hist[i] = 0;   // reuse as rank counter
    __syncthreads();

    for (int e = e0 + tid; e < e1; e += T) {
        int d = dst[e];
        int b = d >> NBITS;
        int r = s_base[b] + atomicAdd(&s_hist[b], 1);
        if (r < BINCAP) {
            int meta = src[e] | ((d & (BINSZ - 1)) << 20);
            staged[(size_t)b * BINCAP + r] = make_int2(meta, __float_as_int(vals[e]));
        }
    }
}

// ---------------------------------------------------------------------------
// Gather (round-7 form): one 512-thread block per 128-dst bin. Established
// at its mixed-hierarchy service-rate ceiling — 63-66 us across occupancy
// 27-61% and five pipeline structures (rounds 1-7). Quarter-wave uint4
// gathers, 8-deep batches pinned with sched_barrier(0).
// ---------------------------------------------------------------------------
#define ACC8(h, v)                                  \
    a0 += (v) * __uint_as_float((h).x << 16);       \
    a1 += (v) * __uint_as_float((h).x & 0xFFFF0000u); \
    a2 += (v) * __uint_as_float((h).y << 16);       \
    a3 += (v) * __uint_as_float((h).y & 0xFFFF0000u); \
    a4 += (v) * __uint_as_float((h).z << 16);       \
    a5 += (v) * __uint_as_float((h).z & 0xFFFF0000u); \
    a6 += (v) * __uint_as_float((h).w << 16);       \
    a7 += (v) * __uint_as_float((h).w & 0xFFFF0000u);

__global__ __launch_bounds__(512) void gather_sort_kernel(const int* __restrict__ cursor,
                                                          const int2* __restrict__ staged,
                                                          const ushort* __restrict__ hb,
                                                          float* __restrict__ out, int N) {
    __shared__ int2 sraw[BINCAP];
    __shared__ int2 sbuf[BINCAP];
    __shared__ int cnt[BINSZ], ofs[BINSZ], cur[BINSZ];
    __shared__ int gofs[16];

    const int b   = blockIdx.x;
    const int tid = threadIdx.x;

    int n = cursor[b * 4];
    if (n > BINCAP) n = BINCAP;

    for (int i = tid; i < BINSZ; i += 512) cnt[i] = 0;
    __syncthreads();

    const int2* sg = staged + (size_t)b * BINCAP;

    // pass 1: histogram + park raw entries in LDS
    for (int i = tid; i < n; i += 512) {
        int2 e = sg[i];
        sraw[i] = e;
        atomicAdd(&cnt[(e.x >> 20) & (BINSZ - 1)], 1);
    }
    __syncthreads();

    // two-level exclusive prefix scan over cnt[128]
    if (tid < 16) {
        int s = 0;
        #pragma unroll
        for (int j = 0; j < 8; ++j) s += cnt[tid * 8 + j];
        gofs[tid] = s;
    }
    __syncthreads();
    if (tid == 0) {
        int run = 0;
        #pragma unroll
        for (int g = 0; g < 16; ++g) { int c = gofs[g]; gofs[g] = run; run += c; }
    }
    __syncthreads();
    if (tid < 16) {
        int run = gofs[tid];
        #pragma unroll
        for (int j = 0; j < 8; ++j) {
            int d = tid * 8 + j;
            int c = cnt[d];
            ofs[d] = run; cur[d] = run; run += c;
        }
    }
    __syncthreads();

    // pass 2: place sorted (LDS -> LDS)
    for (int i = tid; i < n; i += 512) {
        int2 e = sraw[i];
        int pos = atomicAdd(&cur[(e.x >> 20) & (BINSZ - 1)], 1);
        sbuf[pos] = e;
    }
    __syncthreads();

    // quarter-wave accumulate: executor = wave*4 + quarter (32 per block)
    const int ex = (tid >> 6) * 4 + ((tid & 63) >> 4);
    const int m  = tid & 15;

    #pragma unroll
    for (int r = 0; r < 4; ++r) {
        int d  = r * 32 + ex;
        int dg = b * BINSZ + d;
        if (dg >= N) continue;
        int start = ofs[d];
        int c     = cnt[d];

        float a0 = 0.f, a1 = 0.f, a2 = 0.f, a3 = 0.f;
        float a4 = 0.f, a5 = 0.f, a6 = 0.f, a7 = 0.f;
        int j = 0;
        for (; j + 8 <= c; j += 8) {
            int2 e0 = sbuf[start + j];
            int2 e1 = sbuf[start + j + 1];
            int2 e2 = sbuf[start + j + 2];
            int2 e3 = sbuf[start + j + 3];
            int2 e4 = sbuf[start + j + 4];
            int2 e5 = sbuf[start + j + 5];
            int2 e6 = sbuf[start + j + 6];
            int2 e7 = sbuf[start + j + 7];
            __builtin_amdgcn_sched_barrier(0);     // NOTHING crosses
            uint4 h0 = *(const uint4*)(hb + (size_t)(e0.x & 0xFFFFF) * UNITS + m * 8);
            uint4 h1 = *(const uint4*)(hb + (size_t)(e1.x & 0xFFFFF) * UNITS + m * 8);
            uint4 h2 = *(const uint4*)(hb + (size_t)(e2.x & 0xFFFFF) * UNITS + m * 8);
            uint4 h3 = *(const uint4*)(hb + (size_t)(e3.x & 0xFFFFF) * UNITS + m * 8);
            uint4 h4 = *(const uint4*)(hb + (size_t)(e4.x & 0xFFFFF) * UNITS + m * 8);
            uint4 h5 = *(const uint4*)(hb + (size_t)(e5.x & 0xFFFFF) * UNITS + m * 8);
            uint4 h6 = *(const uint4*)(hb + (size_t)(e6.x & 0xFFFFF) * UNITS + m * 8);
            uint4 h7 = *(const uint4*)(hb + (size_t)(e7.x & 0xFFFFF) * UNITS + m * 8);
            __builtin_amdgcn_sched_barrier(0);     // all 8 loads issued before any ACC
            float v0 = __int_as_float(e0.y);
            float v1 = __int_as_float(e1.y);
            float v2 = __int_as_float(e2.y);
            float v3 = __int_as_float(e3.y);
            float v4 = __int_as_float(e4.y);
            float v5 = __int_as_float(e5.y);
            float v6 = __int_as_float(e6.y);
            float v7 = __int_as_float(e7.y);
            ACC8(h0, v0)
            ACC8(h1, v1)
            ACC8(h2, v2)
            ACC8(h3, v3)
            ACC8(h4, v4)
            ACC8(h5, v5)
            ACC8(h6, v6)
            ACC8(h7, v7)
        }
        if (j + 4 <= c) {
            int2 e0 = sbuf[start + j];
            int2 e1 = sbuf[start + j + 1];
            int2 e2 = sbuf[start + j + 2];
            int2 e3 = sbuf[start + j + 3];
            __builtin_amdgcn_sched_barrier(0);
            uint4 h0 = *(const uint4*)(hb + (size_t)(e0.x & 0xFFFFF) * UNITS + m * 8);
            uint4 h1 = *(const uint4*)(hb + (size_t)(e1.x & 0xFFFFF) * UNITS + m * 8);
            uint4 h2 = *(const uint4*)(hb + (size_t)(e2.x & 0xFFFFF) * UNITS + m * 8);
            uint4 h3 = *(const uint4*)(hb + (size_t)(e3.x & 0xFFFFF) * UNITS + m * 8);
            __builtin_amdgcn_sched_barrier(0);
            float v0 = __int_as_float(e0.y);
            float v1 = __int_as_float(e1.y);
            float v2 = __int_as_float(e2.y);
            float v3 = __int_as_float(e3.y);
            ACC8(h0, v0)
            ACC8(h1, v1)
            ACC8(h2, v2)
            ACC8(h3, v3)
            j += 4;
        }
        for (; j < c; ++j) {
            int2 e0 = sbuf[start + j];
            uint4 h0 = *(const uint4*)(hb + (size_t)(e0.x & 0xFFFFF) * UNITS + m * 8);
            float v0 = __int_as_float(e0.y);
            ACC8(h0, v0)
        }

        float* op = out + (size_t)dg * UNITS + m * 8;
        *(floatx4*)op       = (floatx4){a0, a1, a2, a3};
        *(floatx4*)(op + 4) = (floatx4){a4, a5, a6, a7};
    }
}

extern "C" void kernel_launch(void* const* d_in, const int* in_sizes, int n_in,
                              void* d_out, int out_size, void* d_ws, size_t ws_size,
                              hipStream_t stream) {
    const float* x        = (const float*)d_in[0];
    const float* w        = (const float*)d_in[1];
    const int*   adj_src  = (const int*)d_in[2];
    const int*   adj_dst  = (const int*)d_in[3];
    const float* adj_vals = (const float*)d_in[4];
    float*       out      = (float*)d_out;

    const int M = in_sizes[0] / D_FEAT;   // 100000 nodes
    const int E = in_sizes[2];            // 1600000 edges
    const int NB = (M + BINSZ - 1) >> NBITS;   // 782 coarse bins

    // Workspace:
    //   hb:     M*128*2           = 25.6 MB
    //   wT:     128*256*2         = 64 KB
    //   cursor: NB*4 ints         = 12.5 KB
    //   staged: NB*BINCAP*8       = 15.2 MB
    char*   ws  = (char*)d_ws;
    ushort* hb  = (ushort*)ws;
    size_t  off = (size_t)M * UNITS * sizeof(ushort);
    off = (off + 255) & ~(size_t)255;
    ushort* wT  = (ushort*)(ws + off);
    off += (size_t)128 * 256 * sizeof(ushort);
    int*    cursor = (int*)(ws + off);
    off += (size_t)NB * 4 * sizeof(int);
    off = (off + 15) & ~(size_t)15;
    int2*   staged = (int2*)(ws + off);

    wt_prep_kernel<<<128, 256, 0, stream>>>(w, wT, cursor, NB * 4);

    gemm_mfma4_kernel<<<(M + 127) / 128, 512, 0, stream>>>(x, wT, hb, M);

    const int NSCAT = 256;
    const int chunk = (E + NSCAT - 1) / NSCAT;
    coarse_scatter_kernel<<<NSCAT, 1024, 0, stream>>>(adj_src, adj_dst, adj_vals,
                                                      cursor, staged, E, NB, chunk);

    gather_sort_kernel<<<NB, 512, 0, stream>>>(cursor, staged, hb, out, M);
}